// Round 1
// baseline (1333.519 us; speedup 1.0000x reference)
//
#include <hip/hip_runtime.h>
#include <math.h>

// Problem constants (from reference): B=2, T=2048, D=768, H=12, HD=64
#define B_  2
#define T_  2048
#define D_  768
#define H_  12
#define HD_ 64

// ---------------------------------------------------------------------------
// GEMM: C = (X @ W^T + bias) * scale
//   X: [M,K] row-major, W: [N,K] row-major (nn.Linear weight), bias: [N]
//   qkv_layout=1: out[((b*H+h)*T+t)*HD+hd] with m=b*T+t, n=h*HD+hd
//   qkv_layout=0: out[m*N+n]
// 64x64 tile, BK=16, 256 threads, 4x4 micro-tile per thread.
// ---------------------------------------------------------------------------
__global__ __launch_bounds__(256)
void gemm_xwt(const float* __restrict__ X, const float* __restrict__ W,
              const float* __restrict__ bias, float* __restrict__ out,
              int M, int N, int K, float scale, int qkv_layout)
{
    __shared__ float As[64][17];   // +1 pad: conflict-free compute reads
    __shared__ float Bs[64][17];
    const int tid = threadIdx.x;
    const int tx = tid & 15, ty = tid >> 4;
    const int bm = blockIdx.x * 64, bn = blockIdx.y * 64;

    float acc[4][4] = {};
    const float* Xp = X + (size_t)bm * K;
    const float* Wp = W + (size_t)bn * K;

    const int lrow = tid >> 2;          // 0..63
    const int lc4  = (tid & 3) * 4;     // 0,4,8,12

    for (int k0 = 0; k0 < K; k0 += 16) {
        float4 xa = *(const float4*)(Xp + (size_t)lrow * K + k0 + lc4);
        float4 wb = *(const float4*)(Wp + (size_t)lrow * K + k0 + lc4);
        As[lrow][lc4 + 0] = xa.x; As[lrow][lc4 + 1] = xa.y;
        As[lrow][lc4 + 2] = xa.z; As[lrow][lc4 + 3] = xa.w;
        Bs[lrow][lc4 + 0] = wb.x; Bs[lrow][lc4 + 1] = wb.y;
        Bs[lrow][lc4 + 2] = wb.z; Bs[lrow][lc4 + 3] = wb.w;
        __syncthreads();
        #pragma unroll
        for (int kk = 0; kk < 16; ++kk) {
            float a[4], b[4];
            #pragma unroll
            for (int r = 0; r < 4; ++r) a[r] = As[ty * 4 + r][kk];
            #pragma unroll
            for (int c = 0; c < 4; ++c) b[c] = Bs[tx * 4 + c][kk];
            #pragma unroll
            for (int r = 0; r < 4; ++r)
                #pragma unroll
                for (int c = 0; c < 4; ++c)
                    acc[r][c] = fmaf(a[r], b[c], acc[r][c]);
        }
        __syncthreads();
    }

    #pragma unroll
    for (int r = 0; r < 4; ++r) {
        int m = bm + ty * 4 + r;
        #pragma unroll
        for (int c = 0; c < 4; ++c) {
            int n = bn + tx * 4 + c;
            float v = (acc[r][c] + bias[n]) * scale;
            if (qkv_layout) {
                int bb = m >> 11;          // /T_
                int t  = m & (T_ - 1);
                int h  = n >> 6;           // /HD_
                int hd = n & (HD_ - 1);
                out[(((size_t)bb * H_ + h) * T_ + t) * HD_ + hd] = v;
            } else {
                out[(size_t)m * N + n] = v;
            }
        }
    }
}

// ---------------------------------------------------------------------------
// Flash-style attention (fp32): one block = (b, h, 64 q-rows).
//   q,k,v: [B,H,T,HD];  bias: [H,T,T];  mask: [B,1,T,T]
//   ctx out: [B,T,D] at column h*HD+d
// 256 threads as 16x16; each thread owns 4x4 of S and 4x4 of O.
// ---------------------------------------------------------------------------
__global__ __launch_bounds__(256)
void attn_fwd(const float* __restrict__ q, const float* __restrict__ k,
              const float* __restrict__ v, const float* __restrict__ bias,
              const float* __restrict__ mask, float* __restrict__ ctx)
{
    __shared__ float Qs[64][65];   // padded: row varies with ty on read
    __shared__ float Ks[64][65];   // padded: row varies with tx on read
    __shared__ float Vs[64][64];   // unpadded: 2-way conflict only (free)
    __shared__ float Ps[64][65];   // padded: row varies with ty on read

    const int tid = threadIdx.x;
    const int tx = tid & 15, ty = tid >> 4;
    const int bh = blockIdx.y;
    const int b  = bh / H_, h = bh - b * H_;
    const int q0 = blockIdx.x * 64;

    const float* qb  = q + (((size_t)b * H_ + h) * T_ + q0) * HD_;
    const float* kb0 = k + (((size_t)b * H_ + h) * T_) * HD_;
    const float* vb0 = v + (((size_t)b * H_ + h) * T_) * HD_;
    const float* brow = bias + ((size_t)h * T_ + q0) * T_;
    const float* mrow = mask + ((size_t)b * T_ + q0) * T_;

    // stage Q tile: 64x64 floats, 4 x float4 per thread
    #pragma unroll
    for (int i = 0; i < 4; ++i) {
        int idx = tid + 256 * i;        // float4 slot 0..1023
        int row = idx >> 4;
        int c4  = (idx & 15) * 4;
        float4 t4 = *(const float4*)(qb + row * HD_ + c4);
        Qs[row][c4 + 0] = t4.x; Qs[row][c4 + 1] = t4.y;
        Qs[row][c4 + 2] = t4.z; Qs[row][c4 + 3] = t4.w;
    }

    float m_run[4], l_run[4], o[4][4];
    #pragma unroll
    for (int r = 0; r < 4; ++r) {
        m_run[r] = -3.0e38f; l_run[r] = 0.f;
        #pragma unroll
        for (int c = 0; c < 4; ++c) o[r][c] = 0.f;
    }

    for (int s0 = 0; s0 < T_; s0 += 64) {
        // stage K,V tiles
        #pragma unroll
        for (int i = 0; i < 4; ++i) {
            int idx = tid + 256 * i;
            int row = idx >> 4;
            int c4  = (idx & 15) * 4;
            float4 kt = *(const float4*)(kb0 + (size_t)(s0 + row) * HD_ + c4);
            float4 vt = *(const float4*)(vb0 + (size_t)(s0 + row) * HD_ + c4);
            Ks[row][c4 + 0] = kt.x; Ks[row][c4 + 1] = kt.y;
            Ks[row][c4 + 2] = kt.z; Ks[row][c4 + 3] = kt.w;
            Vs[row][c4 + 0] = vt.x; Vs[row][c4 + 1] = vt.y;
            Vs[row][c4 + 2] = vt.z; Vs[row][c4 + 3] = vt.w;
        }
        __syncthreads();

        // S = Q K^T (4x4 per thread)
        float acc[4][4] = {};
        #pragma unroll
        for (int d = 0; d < 64; ++d) {
            float a[4], bb[4];
            #pragma unroll
            for (int r = 0; r < 4; ++r) a[r] = Qs[ty * 4 + r][d];
            #pragma unroll
            for (int c = 0; c < 4; ++c) bb[c] = Ks[tx * 4 + c][d];
            #pragma unroll
            for (int r = 0; r < 4; ++r)
                #pragma unroll
                for (int c = 0; c < 4; ++c)
                    acc[r][c] = fmaf(a[r], bb[c], acc[r][c]);
        }

        // + rel_pos_bias + attention_mask (coalesced float4)
        #pragma unroll
        for (int r = 0; r < 4; ++r) {
            const float* bp = brow + (size_t)(ty * 4 + r) * T_ + s0 + tx * 4;
            const float* mp = mrow + (size_t)(ty * 4 + r) * T_ + s0 + tx * 4;
            float4 bt = *(const float4*)bp;
            float4 mt = *(const float4*)mp;
            acc[r][0] += bt.x + mt.x; acc[r][1] += bt.y + mt.y;
            acc[r][2] += bt.z + mt.z; acc[r][3] += bt.w + mt.w;
        }

        // online softmax (row groups = 16 consecutive lanes)
        #pragma unroll
        for (int r = 0; r < 4; ++r) {
            float mx = fmaxf(fmaxf(acc[r][0], acc[r][1]),
                             fmaxf(acc[r][2], acc[r][3]));
            #pragma unroll
            for (int off = 1; off < 16; off <<= 1)
                mx = fmaxf(mx, __shfl_xor(mx, off));
            float m_new = fmaxf(m_run[r], mx);
            float sc = __expf(m_run[r] - m_new);   // first tile: exp(-3e38)=0
            float ssum = 0.f;
            #pragma unroll
            for (int c = 0; c < 4; ++c) {
                float p = __expf(acc[r][c] - m_new);
                acc[r][c] = p; ssum += p;
            }
            #pragma unroll
            for (int off = 1; off < 16; off <<= 1)
                ssum += __shfl_xor(ssum, off);
            l_run[r] = l_run[r] * sc + ssum;
            m_run[r] = m_new;
            #pragma unroll
            for (int c = 0; c < 4; ++c) o[r][c] *= sc;
        }

        // write P tile
        #pragma unroll
        for (int r = 0; r < 4; ++r)
            #pragma unroll
            for (int c = 0; c < 4; ++c)
                Ps[ty * 4 + r][tx * 4 + c] = acc[r][c];
        __syncthreads();

        // O += P @ V
        #pragma unroll
        for (int j = 0; j < 64; ++j) {
            float p[4], vv[4];
            #pragma unroll
            for (int r = 0; r < 4; ++r) p[r] = Ps[ty * 4 + r][j];
            #pragma unroll
            for (int c = 0; c < 4; ++c) vv[c] = Vs[j][tx * 4 + c];
            #pragma unroll
            for (int r = 0; r < 4; ++r)
                #pragma unroll
                for (int c = 0; c < 4; ++c)
                    o[r][c] = fmaf(p[r], vv[c], o[r][c]);
        }
        __syncthreads();   // protect Ks/Vs/Ps before next tile
    }

    // epilogue: normalize and write ctx[B,T,D]
    #pragma unroll
    for (int r = 0; r < 4; ++r) {
        float inv = 1.0f / l_run[r];
        int t = q0 + ty * 4 + r;
        #pragma unroll
        for (int c = 0; c < 4; ++c) {
            ctx[((size_t)b * T_ + t) * D_ + h * HD_ + tx * 4 + c] = o[r][c] * inv;
        }
    }
}

// ---------------------------------------------------------------------------
extern "C" void kernel_launch(void* const* d_in, const int* in_sizes, int n_in,
                              void* d_out, int out_size, void* d_ws, size_t ws_size,
                              hipStream_t stream) {
    const float* hs   = (const float*)d_in[0];   // [B,T,D]
    const float* mask = (const float*)d_in[1];   // [B,1,T,T]
    const float* bias = (const float*)d_in[2];   // [H,T,T]
    const float* Wq   = (const float*)d_in[3];
    const float* bq   = (const float*)d_in[4];
    const float* Wk   = (const float*)d_in[5];
    const float* bk   = (const float*)d_in[6];
    const float* Wv   = (const float*)d_in[7];
    const float* bv   = (const float*)d_in[8];
    const float* Wo   = (const float*)d_in[9];
    const float* bo   = (const float*)d_in[10];
    float* out = (float*)d_out;

    float* ws = (float*)d_ws;
    const size_t NE = (size_t)B_ * T_ * D_;      // 3,145,728 floats
    float* qw  = ws;
    float* kw  = ws + NE;
    float* vw  = ws + 2 * NE;
    float* ctx = ws + 3 * NE;                    // total 50.3 MB of d_ws

    const int M = B_ * T_;                       // 4096
    dim3 gemm_grid(M / 64, D_ / 64);             // (64, 12)
    const float scale = 0.125f;                  // HD^-0.5 = 1/8

    gemm_xwt<<<gemm_grid, 256, 0, stream>>>(hs, Wq, bq, qw, M, D_, D_, scale, 1);
    gemm_xwt<<<gemm_grid, 256, 0, stream>>>(hs, Wk, bk, kw, M, D_, D_, 1.0f, 1);
    gemm_xwt<<<gemm_grid, 256, 0, stream>>>(hs, Wv, bv, vw, M, D_, D_, 1.0f, 1);

    attn_fwd<<<dim3(T_ / 64, B_ * H_), 256, 0, stream>>>(qw, kw, vw, bias, mask, ctx);

    gemm_xwt<<<gemm_grid, 256, 0, stream>>>(ctx, Wo, bo, out, M, D_, D_, 1.0f, 0);
}

// Round 2
// 479.600 us; speedup vs baseline: 2.7805x; 2.7805x over previous
//
#include <hip/hip_runtime.h>
#include <hip/hip_bf16.h>

// Problem constants: B=2, T=2048, D=768, H=12, HD=64
#define B_  2
#define T_  2048
#define D_  768
#define H_  12
#define HD_ 64

typedef short bf16x8 __attribute__((ext_vector_type(8)));   // 8 bf16 = 4 VGPR (guide §3)
typedef float f32x4  __attribute__((ext_vector_type(4)));   // MFMA 16x16 acc

static __device__ __forceinline__ unsigned short f2bf(float f) {
    union { float f; unsigned u; } v; v.f = f;
    unsigned r = (v.u + 0x7FFFu + ((v.u >> 16) & 1u)) >> 16;   // RNE
    return (unsigned short)r;
}

// ---------------------------------------------------------------------------
// fp32 -> bf16 elementwise convert (16B stores), n8 = n/8
// ---------------------------------------------------------------------------
__global__ void cvt_f32_bf16(const float* __restrict__ in,
                             unsigned short* __restrict__ out, int n8) {
    int i = blockIdx.x * blockDim.x + threadIdx.x;
    int stride = gridDim.x * blockDim.x;
    for (; i < n8; i += stride) {
        float4 a = *(const float4*)(in + (size_t)i * 8);
        float4 b = *(const float4*)(in + (size_t)i * 8 + 4);
        union { unsigned short s[8]; int4 v; } o;
        o.s[0] = f2bf(a.x); o.s[1] = f2bf(a.y); o.s[2] = f2bf(a.z); o.s[3] = f2bf(a.w);
        o.s[4] = f2bf(b.x); o.s[5] = f2bf(b.y); o.s[6] = f2bf(b.z); o.s[7] = f2bf(b.w);
        *(int4*)(out + (size_t)i * 8) = o.v;
    }
}

// ---------------------------------------------------------------------------
// bf16 MFMA GEMM: C = (A @ W^T + bias) * scale
//   A: [4096, 768] bf16 row-major; W: [768, 768] bf16 row-major (= B^T form)
//   mode 0: out fp32 [4096,768];  mode 1: out bf16 in [B,H,T,HD] qkv layout
// 128x128 tile, BK=32, 4 waves (2x2) of 64x64 each, 4x4 frags of 16x16x32.
// LDS row stride 40 ushorts (80B, odd*16B -> ~2-way bank aliasing = free).
// ---------------------------------------------------------------------------
__global__ __launch_bounds__(256)
void gemm_bt_bf16(const unsigned short* __restrict__ A,
                  const unsigned short* __restrict__ Bw,
                  const float* __restrict__ bias,
                  void* __restrict__ out, float scale, int mode)
{
    __shared__ __align__(16) unsigned short As[128 * 40];
    __shared__ __align__(16) unsigned short Bs[128 * 40];

    const int tid  = threadIdx.x;
    const int lane = tid & 63;
    const int wid  = tid >> 6;
    const int wm   = wid >> 1, wn = wid & 1;
    const int l15  = lane & 15, l16 = lane >> 4;
    const int bm   = blockIdx.x * 128, bn = blockIdx.y * 128;

    f32x4 acc[4][4];
    #pragma unroll
    for (int mi = 0; mi < 4; ++mi)
        #pragma unroll
        for (int ni = 0; ni < 4; ++ni)
            acc[mi][ni] = (f32x4){0.f, 0.f, 0.f, 0.f};

    const int r0 = tid >> 2,          o0 = (tid & 3) * 8;          // chunk tid
    const int r1 = (tid + 256) >> 2,  o1 = ((tid + 256) & 3) * 8;  // chunk tid+256

    for (int k0 = 0; k0 < 768; k0 += 32) {
        int4 a0 = *(const int4*)(A  + (size_t)(bm + r0) * 768 + k0 + o0);
        int4 a1 = *(const int4*)(A  + (size_t)(bm + r1) * 768 + k0 + o1);
        int4 b0 = *(const int4*)(Bw + (size_t)(bn + r0) * 768 + k0 + o0);
        int4 b1 = *(const int4*)(Bw + (size_t)(bn + r1) * 768 + k0 + o1);
        *(int4*)(As + r0 * 40 + o0) = a0;
        *(int4*)(As + r1 * 40 + o1) = a1;
        *(int4*)(Bs + r0 * 40 + o0) = b0;
        *(int4*)(Bs + r1 * 40 + o1) = b1;
        __syncthreads();

        bf16x8 af[4], bf[4];
        #pragma unroll
        for (int mi = 0; mi < 4; ++mi)
            af[mi] = *(const bf16x8*)(As + (wm * 64 + mi * 16 + l15) * 40 + l16 * 8);
        #pragma unroll
        for (int ni = 0; ni < 4; ++ni)
            bf[ni] = *(const bf16x8*)(Bs + (wn * 64 + ni * 16 + l15) * 40 + l16 * 8);
        #pragma unroll
        for (int mi = 0; mi < 4; ++mi)
            #pragma unroll
            for (int ni = 0; ni < 4; ++ni)
                acc[mi][ni] = __builtin_amdgcn_mfma_f32_16x16x32_bf16(
                    af[mi], bf[ni], acc[mi][ni], 0, 0, 0);
        __syncthreads();
    }

    // epilogue: C/D layout col = lane&15, row = (lane>>4)*4 + reg  [m89/m91]
    if (mode == 0) {
        float* o = (float*)out;
        #pragma unroll
        for (int ni = 0; ni < 4; ++ni) {
            int col = bn + wn * 64 + ni * 16 + l15;
            float bv = bias[col];
            #pragma unroll
            for (int mi = 0; mi < 4; ++mi)
                #pragma unroll
                for (int reg = 0; reg < 4; ++reg) {
                    int row = bm + wm * 64 + mi * 16 + l16 * 4 + reg;
                    o[(size_t)row * 768 + col] = acc[mi][ni][reg] + bv;
                }
        }
    } else {
        unsigned short* o = (unsigned short*)out;
        #pragma unroll
        for (int ni = 0; ni < 4; ++ni) {
            int col = bn + wn * 64 + ni * 16 + l15;
            float bv = bias[col];
            int h = col >> 6, hd = col & 63;
            #pragma unroll
            for (int mi = 0; mi < 4; ++mi)
                #pragma unroll
                for (int reg = 0; reg < 4; ++reg) {
                    int row = bm + wm * 64 + mi * 16 + l16 * 4 + reg;
                    int bb = row >> 11, t = row & (T_ - 1);
                    float v = (acc[mi][ni][reg] + bv) * scale;
                    o[(((size_t)bb * H_ + h) * T_ + t) * HD_ + hd] = f2bf(v);
                }
        }
    }
}

// ---------------------------------------------------------------------------
// Flash attention, bf16 MFMA. Block = (64 q-rows, one (b,h)); 4 waves x 16 rows.
//   q,k,v: [B,H,T,64] bf16 (q pre-scaled); bias fp32 [H,T,T]; mask fp32 [B,1,T,T]
//   ctx out: bf16 [B,T,D] at col h*64.
// K staged [64][72] (144B stride); V staged transposed Vt[64hd][72].
// ---------------------------------------------------------------------------
__global__ __launch_bounds__(256)
void attn_fwd_mfma(const unsigned short* __restrict__ q,
                   const unsigned short* __restrict__ k,
                   const unsigned short* __restrict__ v,
                   const float* __restrict__ bias,
                   const float* __restrict__ mask,
                   unsigned short* __restrict__ ctx)
{
    __shared__ __align__(16) unsigned short Ks[64 * 72];
    __shared__ __align__(16) unsigned short Vt[64 * 72];
    __shared__ __align__(16) unsigned short Ps[64 * 72];  // wave w owns rows 16w..16w+15

    const int tid  = threadIdx.x;
    const int lane = tid & 63;
    const int wq   = tid >> 6;
    const int l15  = lane & 15, l16 = lane >> 4;
    const int bh   = blockIdx.y;
    const int b    = bh / H_, h = bh % H_;
    const int q0   = blockIdx.x * 64;

    const unsigned short* qb = q + (size_t)bh * T_ * HD_;
    const unsigned short* kb = k + (size_t)bh * T_ * HD_;
    const unsigned short* vb = v + (size_t)bh * T_ * HD_;

    // hoist Q fragments (A-frag: row = lane&15, k = (lane>>4)*8 + j)
    bf16x8 qf[2];
    {
        const unsigned short* qp = qb + (size_t)(q0 + wq * 16 + l15) * HD_;
        qf[0] = *(const bf16x8*)(qp + l16 * 8);
        qf[1] = *(const bf16x8*)(qp + 32 + l16 * 8);
    }

    float m_run[4], l_run[4];
    f32x4 o[4];
    #pragma unroll
    for (int r = 0; r < 4; ++r) {
        m_run[r] = -3.0e38f; l_run[r] = 0.f;
        o[r] = (f32x4){0.f, 0.f, 0.f, 0.f};
    }

    const size_t brow = (size_t)h * T_ * T_ + (size_t)(q0 + wq * 16) * T_;
    const size_t mrow = (size_t)b * T_ * T_ + (size_t)(q0 + wq * 16) * T_;

    for (int s0 = 0; s0 < T_; s0 += 64) {
        // ---- stage K (row-major copy) and V (transposed) ----
        #pragma unroll
        for (int it = 0; it < 2; ++it) {
            int slot = tid + it * 256;
            int row = slot >> 3, c8 = (slot & 7) * 8;
            int4 kv = *(const int4*)(kb + (size_t)(s0 + row) * HD_ + c8);
            *(int4*)(Ks + row * 72 + c8) = kv;
            int key = slot & 63, hd0 = (slot >> 6) * 8;
            int4 vv = *(const int4*)(vb + (size_t)(s0 + key) * HD_ + hd0);
            const unsigned short* vs = (const unsigned short*)&vv;
            #pragma unroll
            for (int e = 0; e < 8; ++e)
                Vt[(hd0 + e) * 72 + key] = vs[e];     // contiguous across lanes: no conflict
        }
        __syncthreads();

        // ---- issue bias+mask loads early (hide under MFMA) ----
        float badd[4][4];
        #pragma unroll
        for (int f = 0; f < 4; ++f)
            #pragma unroll
            for (int reg = 0; reg < 4; ++reg) {
                size_t off = (size_t)(l16 * 4 + reg) * T_ + s0 + f * 16 + l15;
                badd[f][reg] = bias[brow + off] + mask[mrow + off];
            }

        // ---- S = Q K^T ----
        f32x4 s[4];
        #pragma unroll
        for (int f = 0; f < 4; ++f) {
            bf16x8 k0f = *(const bf16x8*)(Ks + (f * 16 + l15) * 72 + l16 * 8);
            bf16x8 k1f = *(const bf16x8*)(Ks + (f * 16 + l15) * 72 + 32 + l16 * 8);
            f32x4 t = (f32x4){0.f, 0.f, 0.f, 0.f};
            t = __builtin_amdgcn_mfma_f32_16x16x32_bf16(qf[0], k0f, t, 0, 0, 0);
            t = __builtin_amdgcn_mfma_f32_16x16x32_bf16(qf[1], k1f, t, 0, 0, 0);
            s[f] = t;
        }

        #pragma unroll
        for (int f = 0; f < 4; ++f)
            #pragma unroll
            for (int reg = 0; reg < 4; ++reg)
                s[f][reg] += badd[f][reg];

        // ---- online softmax: row r = l16*4+reg owned by 16-lane group l16 ----
        float sc[4];
        #pragma unroll
        for (int reg = 0; reg < 4; ++reg) {
            float mx = fmaxf(fmaxf(s[0][reg], s[1][reg]), fmaxf(s[2][reg], s[3][reg]));
            #pragma unroll
            for (int off = 1; off < 16; off <<= 1)
                mx = fmaxf(mx, __shfl_xor(mx, off));
            float m_new = fmaxf(m_run[reg], mx);
            float scv = __expf(m_run[reg] - m_new);
            float ssum = 0.f;
            #pragma unroll
            for (int f = 0; f < 4; ++f) {
                float p = __expf(s[f][reg] - m_new);
                s[f][reg] = p; ssum += p;
            }
            #pragma unroll
            for (int off = 1; off < 16; off <<= 1)
                ssum += __shfl_xor(ssum, off);
            l_run[reg] = l_run[reg] * scv + ssum;
            m_run[reg] = m_new;
            sc[reg] = scv;
        }
        #pragma unroll
        for (int f = 0; f < 4; ++f)
            #pragma unroll
            for (int reg = 0; reg < 4; ++reg)
                o[f][reg] *= sc[reg];

        // ---- P -> bf16 -> per-wave LDS slice ----
        unsigned short* Pw = Ps + wq * 16 * 72;
        #pragma unroll
        for (int f = 0; f < 4; ++f)
            #pragma unroll
            for (int reg = 0; reg < 4; ++reg)
                Pw[(l16 * 4 + reg) * 72 + f * 16 + l15] = f2bf(s[f][reg]);

        // ---- O += P @ V ----
        #pragma unroll
        for (int kc = 0; kc < 2; ++kc) {
            bf16x8 pf = *(const bf16x8*)(Pw + l15 * 72 + kc * 32 + l16 * 8);
            #pragma unroll
            for (int f = 0; f < 4; ++f) {
                bf16x8 vf = *(const bf16x8*)(Vt + (f * 16 + l15) * 72 + kc * 32 + l16 * 8);
                o[f] = __builtin_amdgcn_mfma_f32_16x16x32_bf16(pf, vf, o[f], 0, 0, 0);
            }
        }
        __syncthreads();   // protect Ks/Vt before next tile's staging
    }

    // ---- epilogue: normalize, write ctx bf16 [B,T,D] ----
    unsigned short* cb = ctx + ((size_t)b * T_ + q0 + wq * 16) * D_ + h * HD_;
    #pragma unroll
    for (int reg = 0; reg < 4; ++reg) {
        float inv = 1.f / l_run[reg];
        int r = l16 * 4 + reg;
        #pragma unroll
        for (int f = 0; f < 4; ++f)
            cb[(size_t)r * D_ + f * 16 + l15] = f2bf(o[f][reg] * inv);
    }
}

// ---------------------------------------------------------------------------
extern "C" void kernel_launch(void* const* d_in, const int* in_sizes, int n_in,
                              void* d_out, int out_size, void* d_ws, size_t ws_size,
                              hipStream_t stream) {
    const float* hs   = (const float*)d_in[0];
    const float* mask = (const float*)d_in[1];
    const float* bias = (const float*)d_in[2];
    const float* Wq   = (const float*)d_in[3];
    const float* bq   = (const float*)d_in[4];
    const float* Wk   = (const float*)d_in[5];
    const float* bk   = (const float*)d_in[6];
    const float* Wv   = (const float*)d_in[7];
    const float* bv   = (const float*)d_in[8];
    const float* Wo   = (const float*)d_in[9];
    const float* bo   = (const float*)d_in[10];
    float* out = (float*)d_out;

    const size_t NE = (size_t)B_ * T_ * D_;      // 3,145,728
    const size_t WE = (size_t)D_ * D_;           // 589,824
    unsigned short* ws = (unsigned short*)d_ws;
    unsigned short* hs_bf = ws;                  // NE
    unsigned short* Wq_bf = hs_bf + NE;          // WE
    unsigned short* Wk_bf = Wq_bf + WE;
    unsigned short* Wv_bf = Wk_bf + WE;
    unsigned short* Wo_bf = Wv_bf + WE;
    unsigned short* qw    = Wo_bf + WE;          // NE (each, [B,H,T,HD])
    unsigned short* kw    = qw + NE;
    unsigned short* vw    = kw + NE;
    unsigned short* ctxb  = vw + NE;             // NE -> total ~36.2 MB

    // converts
    {
        int n8 = (int)(NE / 8);
        cvt_f32_bf16<<<dim3((n8 + 255) / 256 > 2048 ? 2048 : (n8 + 255) / 256), 256, 0, stream>>>(hs, hs_bf, n8);
        int w8 = (int)(WE / 8);
        dim3 wg((w8 + 255) / 256);
        cvt_f32_bf16<<<wg, 256, 0, stream>>>(Wq, Wq_bf, w8);
        cvt_f32_bf16<<<wg, 256, 0, stream>>>(Wk, Wk_bf, w8);
        cvt_f32_bf16<<<wg, 256, 0, stream>>>(Wv, Wv_bf, w8);
        cvt_f32_bf16<<<wg, 256, 0, stream>>>(Wo, Wo_bf, w8);
    }

    dim3 ggrid(32, 6);   // M/128 x N/128
    const float scale = 0.125f;                  // HD^-0.5
    gemm_bt_bf16<<<ggrid, 256, 0, stream>>>(hs_bf, Wq_bf, bq, qw, scale, 1);
    gemm_bt_bf16<<<ggrid, 256, 0, stream>>>(hs_bf, Wk_bf, bk, kw, 1.0f, 1);
    gemm_bt_bf16<<<ggrid, 256, 0, stream>>>(hs_bf, Wv_bf, bv, vw, 1.0f, 1);

    attn_fwd_mfma<<<dim3(T_ / 64, B_ * H_), 256, 0, stream>>>(qw, kw, vw, bias, mask, ctxb);

    gemm_bt_bf16<<<ggrid, 256, 0, stream>>>(ctxb, Wo_bf, bo, out, 1.0f, 0);
}

// Round 3
// 477.016 us; speedup vs baseline: 2.7955x; 1.0054x over previous
//
#include <hip/hip_runtime.h>

// Problem constants: B=2, T=2048, D=768, H=12, HD=64
#define B_  2
#define T_  2048
#define D_  768
#define H_  12
#define HD_ 64

typedef short bf16x8 __attribute__((ext_vector_type(8)));   // 8 bf16 = 4 VGPR
typedef float f32x4  __attribute__((ext_vector_type(4)));   // MFMA 16x16 acc
typedef unsigned int u32;

static __device__ __forceinline__ unsigned short f2bf(float f) {
    union { float f; unsigned u; } v; v.f = f;
    unsigned r = (v.u + 0x7FFFu + ((v.u >> 16) & 1u)) >> 16;   // RNE
    return (unsigned short)r;
}

// ---------------------------------------------------------------------------
// fp32 -> bf16 convert, grid-stride, 8 elems/thread
// ---------------------------------------------------------------------------
__global__ void cvt_f32_bf16(const float* __restrict__ in,
                             unsigned short* __restrict__ out, int n8) {
    int i = blockIdx.x * blockDim.x + threadIdx.x;
    int stride = gridDim.x * blockDim.x;
    for (; i < n8; i += stride) {
        float4 a = *(const float4*)(in + (size_t)i * 8);
        float4 b = *(const float4*)(in + (size_t)i * 8 + 4);
        union { unsigned short s[8]; int4 v; } o;
        o.s[0] = f2bf(a.x); o.s[1] = f2bf(a.y); o.s[2] = f2bf(a.z); o.s[3] = f2bf(a.w);
        o.s[4] = f2bf(b.x); o.s[5] = f2bf(b.y); o.s[6] = f2bf(b.z); o.s[7] = f2bf(b.w);
        *(int4*)(out + (size_t)i * 8) = o.v;
    }
}

// convert 4 weight matrices [768x768] into one contiguous bf16 buffer
// (rows 0-2303 = Wq|Wk|Wv for the fused QKV GEMM, rows 2304.. = Wo)
__global__ void cvt_weights(const float* __restrict__ w0, const float* __restrict__ w1,
                            const float* __restrict__ w2, const float* __restrict__ w3,
                            unsigned short* __restrict__ out, int n8) {
    const float* src = (blockIdx.y == 0) ? w0 : (blockIdx.y == 1) ? w1
                     : (blockIdx.y == 2) ? w2 : w3;
    unsigned short* dst = out + (size_t)blockIdx.y * (D_ * D_);
    int i = blockIdx.x * blockDim.x + threadIdx.x;
    int stride = gridDim.x * blockDim.x;
    for (; i < n8; i += stride) {
        float4 a = *(const float4*)(src + (size_t)i * 8);
        float4 b = *(const float4*)(src + (size_t)i * 8 + 4);
        union { unsigned short s[8]; int4 v; } o;
        o.s[0] = f2bf(a.x); o.s[1] = f2bf(a.y); o.s[2] = f2bf(a.z); o.s[3] = f2bf(a.w);
        o.s[4] = f2bf(b.x); o.s[5] = f2bf(b.y); o.s[6] = f2bf(b.z); o.s[7] = f2bf(b.w);
        *(int4*)(dst + (size_t)i * 8) = o.v;
    }
}

// ---------------------------------------------------------------------------
// bf16 MFMA GEMM, m97-style: BM=128, BN=64, BK=32, global_load_lds staging.
//   A: [4096][768] bf16; W: [NW][768] bf16 (NW = 2304 fused-QKV or 768)
//   mode 1: epilogue routes to q/k/v [B,H,T,HD] bf16 (scale on q section)
//   mode 0: fp32 out [4096][768] + bias
// 4 waves as 2x2 (wave tile 64x32), 4x2 frags of 16x16x32. Linear LDS.
// ---------------------------------------------------------------------------
__global__ __launch_bounds__(256)
void gemm_bt_lds(const unsigned short* __restrict__ A,
                 const unsigned short* __restrict__ W,
                 const float* __restrict__ b0, const float* __restrict__ b1,
                 const float* __restrict__ b2,
                 void* __restrict__ outp, int mode)
{
    __shared__ __align__(16) unsigned short As[128 * 32];
    __shared__ __align__(16) unsigned short Bs[64 * 32];

    const int tid  = threadIdx.x;
    const int lane = tid & 63;
    const int wid  = tid >> 6;
    const int wm   = wid >> 1, wn = wid & 1;
    const int l15  = lane & 15, l16 = lane >> 4;
    const int bm   = blockIdx.x * 128, bn = blockIdx.y * 64;

    f32x4 acc[4][2];
    #pragma unroll
    for (int mi = 0; mi < 4; ++mi)
        #pragma unroll
        for (int ni = 0; ni < 2; ++ni)
            acc[mi][ni] = (f32x4){0.f, 0.f, 0.f, 0.f};

    const int srow = lane >> 2;           // 0..15 within chunk
    const int scol = (lane & 3) * 8;      // ushort offset of 16B chunk

    for (int k0 = 0; k0 < 768; k0 += 32) {
        // staging: 12 x 1KB chunks (8 A + 4 B), 3 per wave, gload_lds width 16
        #pragma unroll
        for (int j = 0; j < 3; ++j) {
            int c = wid * 3 + j;
            const unsigned short* src;
            unsigned short* dst;
            if (c < 8) {
                src = A + (size_t)(bm + c * 16 + srow) * 768 + k0 + scol;
                dst = As + c * 512;
            } else {
                src = W + (size_t)(bn + (c - 8) * 16 + srow) * 768 + k0 + scol;
                dst = Bs + (c - 8) * 512;
            }
            __builtin_amdgcn_global_load_lds(
                (const __attribute__((address_space(1))) u32*)src,
                (__attribute__((address_space(3))) u32*)dst, 16, 0, 0);
        }
        __syncthreads();

        bf16x8 af[4], bfr[2];
        #pragma unroll
        for (int mi = 0; mi < 4; ++mi)
            af[mi] = *(const bf16x8*)(As + (wm * 64 + mi * 16 + l15) * 32 + l16 * 8);
        #pragma unroll
        for (int ni = 0; ni < 2; ++ni)
            bfr[ni] = *(const bf16x8*)(Bs + (wn * 32 + ni * 16 + l15) * 32 + l16 * 8);
        #pragma unroll
        for (int mi = 0; mi < 4; ++mi)
            #pragma unroll
            for (int ni = 0; ni < 2; ++ni)
                acc[mi][ni] = __builtin_amdgcn_mfma_f32_16x16x32_bf16(
                    af[mi], bfr[ni], acc[mi][ni], 0, 0, 0);
        __syncthreads();
    }

    // epilogue: C/D layout col = lane&15, row = (lane>>4)*4 + reg
    if (mode == 1) {
        const int sel = bn / 768;                       // 0=q 1=k 2=v (uniform)
        const float* bp = (sel == 0) ? b0 : (sel == 1) ? b1 : b2;
        const float scale = (sel == 0) ? 0.125f : 1.0f;
        unsigned short* o = (unsigned short*)outp + (size_t)sel * (B_ * T_ * D_);
        #pragma unroll
        for (int ni = 0; ni < 2; ++ni) {
            int cg = bn - sel * 768 + wn * 32 + ni * 16 + l15;
            float bv = bp[cg];
            int h = cg >> 6, hd = cg & 63;
            #pragma unroll
            for (int mi = 0; mi < 4; ++mi)
                #pragma unroll
                for (int reg = 0; reg < 4; ++reg) {
                    int row = bm + wm * 64 + mi * 16 + l16 * 4 + reg;
                    int bb = row >> 11, t = row & (T_ - 1);
                    float v = (acc[mi][ni][reg] + bv) * scale;
                    o[(((size_t)bb * H_ + h) * T_ + t) * HD_ + hd] = f2bf(v);
                }
        }
    } else {
        float* o = (float*)outp;
        #pragma unroll
        for (int ni = 0; ni < 2; ++ni) {
            int col = bn + wn * 32 + ni * 16 + l15;
            float bv = b0[col];
            #pragma unroll
            for (int mi = 0; mi < 4; ++mi)
                #pragma unroll
                for (int reg = 0; reg < 4; ++reg) {
                    int row = bm + wm * 64 + mi * 16 + l16 * 4 + reg;
                    o[(size_t)row * 768 + col] = acc[mi][ni][reg] + bv;
                }
        }
    }
}

// ---------------------------------------------------------------------------
// Flash attention, swapped-QK^T bf16 MFMA. Block = 64 q-rows of one (b,h).
//   S^T = mfma(K, Q): each lane owns ONE q-row (lane&15) x 16 keys
//   -> scalar m/l per thread, 4 shuffles per softmax, float4 bias/mask loads.
// ---------------------------------------------------------------------------
__global__ __launch_bounds__(256)
void attn_fwd_mfma(const unsigned short* __restrict__ q,
                   const unsigned short* __restrict__ k,
                   const unsigned short* __restrict__ v,
                   const float* __restrict__ bias,
                   const float* __restrict__ mask,
                   unsigned short* __restrict__ ctx)
{
    __shared__ __align__(16) unsigned short Ks[64 * 72];
    __shared__ __align__(16) unsigned short Vt[64 * 72];
    __shared__ __align__(16) unsigned short Ps[64 * 72];  // wave w: rows 16w..16w+15 = its q-rows

    const int tid  = threadIdx.x;
    const int lane = tid & 63;
    const int wq   = tid >> 6;
    const int l15  = lane & 15, l16 = lane >> 4;
    const int bh   = blockIdx.y;
    const int b    = bh / H_, h = bh % H_;
    const int q0   = blockIdx.x * 64;

    const unsigned short* qb = q + (size_t)bh * T_ * HD_;
    const unsigned short* kb = k + (size_t)bh * T_ * HD_;
    const unsigned short* vb = v + (size_t)bh * T_ * HD_;

    // Q fragment (B-operand of swapped mfma): q-row = lane&15, d = (lane>>4)*8+j
    bf16x8 qf[2];
    {
        const unsigned short* qp = qb + (size_t)(q0 + wq * 16 + l15) * HD_;
        qf[0] = *(const bf16x8*)(qp + l16 * 8);
        qf[1] = *(const bf16x8*)(qp + 32 + l16 * 8);
    }

    float m_run = -3.0e38f, l_run = 0.f;
    f32x4 o[4];
    #pragma unroll
    for (int f = 0; f < 4; ++f) o[f] = (f32x4){0.f, 0.f, 0.f, 0.f};

    // per-thread bias/mask row base (this thread's q-row)
    const size_t brow = (size_t)h * T_ * T_ + (size_t)(q0 + wq * 16 + l15) * T_;
    const size_t mrow = (size_t)b * T_ * T_ + (size_t)(q0 + wq * 16 + l15) * T_;

    for (int s0 = 0; s0 < T_; s0 += 64) {
        // ---- stage K (row-major, pad 72) and V transposed ----
        #pragma unroll
        for (int it = 0; it < 2; ++it) {
            int slot = tid + it * 256;
            int row = slot >> 3, c8 = (slot & 7) * 8;
            int4 kv = *(const int4*)(kb + (size_t)(s0 + row) * HD_ + c8);
            *(int4*)(Ks + row * 72 + c8) = kv;
            int key = slot & 63, hd0 = (slot >> 6) * 8;
            int4 vv = *(const int4*)(vb + (size_t)(s0 + key) * HD_ + hd0);
            const unsigned short* vs = (const unsigned short*)&vv;
            #pragma unroll
            for (int e = 0; e < 8; ++e)
                Vt[(hd0 + e) * 72 + key] = vs[e];
        }

        // ---- issue bias+mask float4 loads (latency hides under barrier+QK) ----
        float4 bv4[4], mv4[4];
        #pragma unroll
        for (int f = 0; f < 4; ++f) {
            bv4[f] = *(const float4*)(bias + brow + s0 + f * 16 + l16 * 4);
            mv4[f] = *(const float4*)(mask + mrow + s0 + f * 16 + l16 * 4);
        }
        __syncthreads();

        // ---- S^T = mfma(K, Q): row = key (l16*4+reg within f-block), col = q ----
        f32x4 s[4];
        #pragma unroll
        for (int f = 0; f < 4; ++f) {
            bf16x8 k0f = *(const bf16x8*)(Ks + (f * 16 + l15) * 72 + l16 * 8);
            bf16x8 k1f = *(const bf16x8*)(Ks + (f * 16 + l15) * 72 + 32 + l16 * 8);
            f32x4 t = (f32x4){0.f, 0.f, 0.f, 0.f};
            t = __builtin_amdgcn_mfma_f32_16x16x32_bf16(k0f, qf[0], t, 0, 0, 0);
            t = __builtin_amdgcn_mfma_f32_16x16x32_bf16(k1f, qf[1], t, 0, 0, 0);
            s[f] = t;
        }

        // bias + mask: key = f*16 + l16*4 + reg  -> float4 component = reg
        #pragma unroll
        for (int f = 0; f < 4; ++f) {
            const float* pb = (const float*)&bv4[f];
            const float* pm = (const float*)&mv4[f];
            #pragma unroll
            for (int reg = 0; reg < 4; ++reg)
                s[f][reg] += pb[reg] + pm[reg];
        }

        // ---- online softmax, one q-row per thread ----
        float mx = s[0][0];
        #pragma unroll
        for (int f = 0; f < 4; ++f)
            #pragma unroll
            for (int reg = 0; reg < 4; ++reg)
                mx = fmaxf(mx, s[f][reg]);
        mx = fmaxf(mx, __shfl_xor(mx, 16));
        mx = fmaxf(mx, __shfl_xor(mx, 32));
        float m_new = fmaxf(m_run, mx);
        float scv = __expf(m_run - m_new);
        float psum = 0.f;
        #pragma unroll
        for (int f = 0; f < 4; ++f)
            #pragma unroll
            for (int reg = 0; reg < 4; ++reg) {
                float p = __expf(s[f][reg] - m_new);
                s[f][reg] = p; psum += p;
            }
        psum += __shfl_xor(psum, 16);
        psum += __shfl_xor(psum, 32);
        l_run = l_run * scv + psum;
        m_run = m_new;

        // O-rescale: o rows are q = l16*4+reg; sc lives at lane l15 = that q
        float scq[4];
        #pragma unroll
        for (int reg = 0; reg < 4; ++reg) scq[reg] = __shfl(scv, l16 * 4 + reg);
        #pragma unroll
        for (int f = 0; f < 4; ++f)
            #pragma unroll
            for (int reg = 0; reg < 4; ++reg)
                o[f][reg] *= scq[reg];

        // ---- P -> bf16 -> per-wave LDS [q][key] (ushort4 = 4 consecutive keys) ----
        unsigned short* Pw = Ps + wq * 16 * 72;
        #pragma unroll
        for (int f = 0; f < 4; ++f) {
            ushort4 pk;
            pk.x = f2bf(s[f][0]); pk.y = f2bf(s[f][1]);
            pk.z = f2bf(s[f][2]); pk.w = f2bf(s[f][3]);
            *(ushort4*)(Pw + l15 * 72 + f * 16 + l16 * 4) = pk;
        }

        // ---- O += P @ V (normal layout: A=P rows=q, B=V^T cols=d) ----
        #pragma unroll
        for (int kc = 0; kc < 2; ++kc) {
            bf16x8 pf = *(const bf16x8*)(Pw + l15 * 72 + kc * 32 + l16 * 8);
            #pragma unroll
            for (int f = 0; f < 4; ++f) {
                bf16x8 vf = *(const bf16x8*)(Vt + (f * 16 + l15) * 72 + kc * 32 + l16 * 8);
                o[f] = __builtin_amdgcn_mfma_f32_16x16x32_bf16(pf, vf, o[f], 0, 0, 0);
            }
        }
        __syncthreads();   // protect Ks/Vt/Ps before next tile's staging
    }

    // ---- epilogue: o rows q = l16*4+reg, cols d = f*16+l15; l_run at lane q ----
    float linv[4];
    #pragma unroll
    for (int reg = 0; reg < 4; ++reg)
        linv[reg] = 1.0f / __shfl(l_run, l16 * 4 + reg);
    #pragma unroll
    for (int reg = 0; reg < 4; ++reg) {
        int t = q0 + wq * 16 + l16 * 4 + reg;
        unsigned short* cb = ctx + ((size_t)b * T_ + t) * D_ + h * HD_;
        #pragma unroll
        for (int f = 0; f < 4; ++f)
            cb[f * 16 + l15] = f2bf(o[f][reg] * linv[reg]);
    }
}

// ---------------------------------------------------------------------------
extern "C" void kernel_launch(void* const* d_in, const int* in_sizes, int n_in,
                              void* d_out, int out_size, void* d_ws, size_t ws_size,
                              hipStream_t stream) {
    const float* hs   = (const float*)d_in[0];
    const float* mask = (const float*)d_in[1];
    const float* bias = (const float*)d_in[2];
    const float* Wq   = (const float*)d_in[3];
    const float* bq   = (const float*)d_in[4];
    const float* Wk   = (const float*)d_in[5];
    const float* bk   = (const float*)d_in[6];
    const float* Wv   = (const float*)d_in[7];
    const float* bv   = (const float*)d_in[8];
    const float* Wo   = (const float*)d_in[9];
    const float* bo   = (const float*)d_in[10];
    float* out = (float*)d_out;

    const size_t NE = (size_t)B_ * T_ * D_;      // 3,145,728
    const size_t WE = (size_t)D_ * D_;           // 589,824
    unsigned short* ws = (unsigned short*)d_ws;
    unsigned short* hs_bf = ws;                  // NE
    unsigned short* wbf   = hs_bf + NE;          // 4*WE: Wq|Wk|Wv|Wo
    unsigned short* qkv   = wbf + 4 * WE;        // 3*NE: q|k|v in [B,H,T,HD]
    unsigned short* ctxb  = qkv + 3 * NE;        // NE

    cvt_f32_bf16<<<dim3(1536), 256, 0, stream>>>(hs, hs_bf, (int)(NE / 8));
    cvt_weights<<<dim3(288, 4), 256, 0, stream>>>(Wq, Wk, Wv, Wo, wbf, (int)(WE / 8));

    // fused QKV GEMM: N = 2304 (rows of wbf), 32 x 36 = 1152 blocks
    gemm_bt_lds<<<dim3(32, 36), 256, 0, stream>>>(hs_bf, wbf, bq, bk, bv, qkv, 1);

    attn_fwd_mfma<<<dim3(T_ / 64, B_ * H_), 256, 0, stream>>>(
        qkv, qkv + NE, qkv + 2 * NE, bias, mask, ctxb);

    // out projection: W rows 2304..3071 of wbf
    gemm_bt_lds<<<dim3(32, 12), 256, 0, stream>>>(ctxb, wbf + 3 * WE, bo, nullptr, nullptr, out, 0);
}